// Round 1
// baseline (153.629 us; speedup 1.0000x reference)
//
#include <hip/hip_runtime.h>
#include <hip/hip_bf16.h>
#include <stdint.h>

#define NROWS 32768
#define DDIM  512
#define FDIM  64

typedef __attribute__((ext_vector_type(4))) float f32x4;
typedef __attribute__((ext_vector_type(8))) short bf16x8;

static __device__ __forceinline__ unsigned short f2bf(float x) {
    __hip_bfloat16 h = __float2bfloat16(x);
    return __builtin_bit_cast(unsigned short, h);
}

// Kernel 1: one wave per reduction row.
// rows [0, F*D):      M[f][d] = V[f][d] + dot(W[f][d][:], x2)   (bf16 out)
// rows [F*D, F*D+F):  c[f]    = b[f]    + dot(V[f][512:], x2)   (fp32 out)
__global__ __launch_bounds__(256) void prep_kernel(
    const float* __restrict__ x2,
    const float* __restrict__ V,
    const float* __restrict__ W,
    const float* __restrict__ b,
    unsigned short* __restrict__ Mout,
    float* __restrict__ cout)
{
    int wave = (blockIdx.x * 256 + threadIdx.x) >> 6;
    int lane = threadIdx.x & 63;

    const float4* src;
    if (wave < FDIM * DDIM) {
        src = (const float4*)(W + (size_t)wave * DDIM);
    } else {
        int f = wave - FDIM * DDIM;
        src = (const float4*)(V + (size_t)f * (2 * DDIM) + DDIM);
    }
    const float4* xx = (const float4*)x2;

    float4 a0 = src[lane];
    float4 a1 = src[lane + 64];
    float4 x0 = xx[lane];
    float4 x1v = xx[lane + 64];

    float s = a0.x * x0.x + a0.y * x0.y + a0.z * x0.z + a0.w * x0.w
            + a1.x * x1v.x + a1.y * x1v.y + a1.z * x1v.z + a1.w * x1v.w;

    #pragma unroll
    for (int m = 32; m >= 1; m >>= 1) s += __shfl_xor(s, m);

    if (lane == 0) {
        if (wave < FDIM * DDIM) {
            int f = wave >> 9, d = wave & 511;
            float mval = s + V[(size_t)f * (2 * DDIM) + d];
            Mout[wave] = f2bf(mval);
        } else {
            int f = wave - FDIM * DDIM;
            cout[f] = s + b[f];
        }
    }
}

// Kernel 2: fm = x1 @ M^T + c ; denom = max(sum|fm|, eps) ; out = relu(fm/denom) @ U
// Block = 256 thr (4 waves), 64 rows per block, full F=64 per wave via 4 MFMA tiles.
__global__ __launch_bounds__(256) void main_kernel(
    const float* __restrict__ x1,
    const unsigned short* __restrict__ Mg,   // bf16 [64][512]
    const float* __restrict__ cg,            // [64]
    const float* __restrict__ U,             // [64]
    float* __restrict__ out)                 // [32768]
{
    __shared__ uint4 Mlds[4096];   // 64 KB, stored in MFMA B-frag order [ks][t][lane]

    int tid = threadIdx.x;

    // Stage M into LDS in frag order: dst idx = it*256+tid (linear, conflict-free writes).
    #pragma unroll
    for (int it = 0; it < 16; ++it) {
        int idx = it * 256 + tid;
        int lane = idx & 63;
        int t    = (idx >> 6) & 3;
        int ks   = idx >> 8;
        int f = t * 16 + (lane & 15);
        int e = ks * 32 + ((lane >> 4) << 3);
        Mlds[idx] = *(const uint4*)(Mg + f * DDIM + e);
    }
    __syncthreads();

    int wave = tid >> 6;
    int lane = tid & 63;
    int q  = lane >> 4;     // quad
    int fl = lane & 15;

    int row0 = blockIdx.x * 64 + wave * 16;
    const float* arow = x1 + (size_t)(row0 + fl) * DDIM + q * 8;

    const bf16x8* Mf = (const bf16x8*)Mlds;

    f32x4 acc0 = {0.f,0.f,0.f,0.f}, acc1 = {0.f,0.f,0.f,0.f};
    f32x4 acc2 = {0.f,0.f,0.f,0.f}, acc3 = {0.f,0.f,0.f,0.f};

    #pragma unroll 4
    for (int ks = 0; ks < 16; ++ks) {
        float4 av0 = *(const float4*)(arow + ks * 32);
        float4 av1 = *(const float4*)(arow + ks * 32 + 4);

        union { bf16x8 v; unsigned short u[8]; } af;
        af.u[0] = f2bf(av0.x); af.u[1] = f2bf(av0.y);
        af.u[2] = f2bf(av0.z); af.u[3] = f2bf(av0.w);
        af.u[4] = f2bf(av1.x); af.u[5] = f2bf(av1.y);
        af.u[6] = f2bf(av1.z); af.u[7] = f2bf(av1.w);

        bf16x8 b0 = Mf[(ks * 4 + 0) * 64 + lane];
        bf16x8 b1 = Mf[(ks * 4 + 1) * 64 + lane];
        bf16x8 b2 = Mf[(ks * 4 + 2) * 64 + lane];
        bf16x8 b3 = Mf[(ks * 4 + 3) * 64 + lane];

        acc0 = __builtin_amdgcn_mfma_f32_16x16x32_bf16(af.v, b0, acc0, 0, 0, 0);
        acc1 = __builtin_amdgcn_mfma_f32_16x16x32_bf16(af.v, b1, acc1, 0, 0, 0);
        acc2 = __builtin_amdgcn_mfma_f32_16x16x32_bf16(af.v, b2, acc2, 0, 0, 0);
        acc3 = __builtin_amdgcn_mfma_f32_16x16x32_bf16(af.v, b3, acc3, 0, 0, 0);
    }

    // Epilogue. C/D layout: col(f_local)=lane&15, row=q*4+reg.
    float cf0 = cg[fl], cf1 = cg[16 + fl], cf2 = cg[32 + fl], cf3 = cg[48 + fl];
    float uf0 = U[fl],  uf1 = U[16 + fl],  uf2 = U[32 + fl],  uf3 = U[48 + fl];

    #pragma unroll
    for (int r = 0; r < 4; ++r) {
        float f0 = acc0[r] + cf0;
        float f1 = acc1[r] + cf1;
        float f2 = acc2[r] + cf2;
        float f3 = acc3[r] + cf3;

        float s = fabsf(f0) + fabsf(f1) + fabsf(f2) + fabsf(f3);
        s += __shfl_xor(s, 1); s += __shfl_xor(s, 2);
        s += __shfl_xor(s, 4); s += __shfl_xor(s, 8);
        float denom = fmaxf(s, 1e-12f);

        float o = fmaxf(f0, 0.f) * uf0 + fmaxf(f1, 0.f) * uf1
                + fmaxf(f2, 0.f) * uf2 + fmaxf(f3, 0.f) * uf3;
        o += __shfl_xor(o, 1); o += __shfl_xor(o, 2);
        o += __shfl_xor(o, 4); o += __shfl_xor(o, 8);

        if (fl == 0) {
            out[row0 + q * 4 + r] = o / denom;
        }
    }
}

extern "C" void kernel_launch(void* const* d_in, const int* in_sizes, int n_in,
                              void* d_out, int out_size, void* d_ws, size_t ws_size,
                              hipStream_t stream) {
    const float* x1 = (const float*)d_in[0];
    const float* x2 = (const float*)d_in[1];
    const float* V  = (const float*)d_in[2];
    const float* W  = (const float*)d_in[3];
    const float* b  = (const float*)d_in[4];
    const float* U  = (const float*)d_in[5];
    float* outp = (float*)d_out;

    unsigned short* M = (unsigned short*)d_ws;                  // 64*512 bf16 = 64 KB
    float* c          = (float*)((char*)d_ws + FDIM * DDIM * 2); // 64 fp32

    // rows = F*D (M) + F (c) = 32832; 4 waves/block -> 8208 blocks
    prep_kernel<<<8208, 256, 0, stream>>>(x2, V, W, b, M, c);
    // 32768 rows / 64 per block = 512 blocks
    main_kernel<<<512, 256, 0, stream>>>(x1, M, c, U, outp);
}

// Round 2
// 152.647 us; speedup vs baseline: 1.0064x; 1.0064x over previous
//
#include <hip/hip_runtime.h>
#include <hip/hip_bf16.h>
#include <stdint.h>

#define NROWS 32768
#define DDIM  512
#define FDIM  64

typedef __attribute__((ext_vector_type(4))) float f32x4;
typedef __attribute__((ext_vector_type(8))) short bf16x8;

// RNE fp32->bf16 (no NaN path: inputs are finite randn products)
static __device__ __forceinline__ unsigned short f2bf_rne(float x) {
    unsigned u = __builtin_bit_cast(unsigned, x);
    u += 0x7fffu + ((u >> 16) & 1u);
    return (unsigned short)(u >> 16);
}
// pack two fp32 -> bf16x2 in one u32 (compiler folds the merge to v_perm)
static __device__ __forceinline__ unsigned pack2_bf16(float a, float b) {
    unsigned ua = __builtin_bit_cast(unsigned, a);
    unsigned ub = __builtin_bit_cast(unsigned, b);
    ua += 0x7fffu + ((ua >> 16) & 1u);
    ub += 0x7fffu + ((ub >> 16) & 1u);
    return (ua >> 16) | (ub & 0xffff0000u);
}

static __device__ __forceinline__ void async_copy16(const void* g, void* l) {
    __builtin_amdgcn_global_load_lds(
        (const __attribute__((address_space(1))) unsigned int*)g,
        (__attribute__((address_space(3))) unsigned int*)l,
        16, 0, 0);
}

// Kernel 1: one wave per reduction row.
// rows [0, F*D):      M[fragidx(f,d)] = V[f][d] + dot(W[f][d][:], x2)  (bf16, MFMA B-frag order)
// rows [F*D, F*D+F):  c[f] = b[f] + dot(V[f][512:], x2)                (fp32)
__global__ __launch_bounds__(256) void prep_kernel(
    const float* __restrict__ x2,
    const float* __restrict__ V,
    const float* __restrict__ W,
    const float* __restrict__ b,
    unsigned short* __restrict__ Mout,
    float* __restrict__ cout)
{
    int wave = (blockIdx.x * 256 + threadIdx.x) >> 6;
    int lane = threadIdx.x & 63;

    const float4* src;
    if (wave < FDIM * DDIM) {
        src = (const float4*)(W + (size_t)wave * DDIM);
    } else {
        int f = wave - FDIM * DDIM;
        src = (const float4*)(V + (size_t)f * (2 * DDIM) + DDIM);
    }
    const float4* xx = (const float4*)x2;

    float4 a0 = src[lane];
    float4 a1 = src[lane + 64];
    float4 x0 = xx[lane];
    float4 x1v = xx[lane + 64];

    float s = a0.x * x0.x + a0.y * x0.y + a0.z * x0.z + a0.w * x0.w
            + a1.x * x1v.x + a1.y * x1v.y + a1.z * x1v.z + a1.w * x1v.w;

    #pragma unroll
    for (int m = 32; m >= 1; m >>= 1) s += __shfl_xor(s, m);

    if (lane == 0) {
        if (wave < FDIM * DDIM) {
            int f = wave >> 9, d = wave & 511;
            float mval = s + V[(size_t)f * (2 * DDIM) + d];
            // MFMA B-frag order so main's staging is a linear copy:
            // frag u4-index = (ks*4 + t)*64 + lane, lane = sub*16 + fl
            int t  = f >> 4, fl = f & 15;
            int ks = d >> 5, sub = (d >> 3) & 3, j = d & 7;
            int fragidx = (((ks * 4 + t) * 64 + sub * 16 + fl) << 3) + j;
            Mout[fragidx] = f2bf_rne(mval);
        } else {
            int f = wave - FDIM * DDIM;
            cout[f] = s + b[f];
        }
    }
}

// Kernel 2: fm = x1 @ M^T + c ; denom = max(sum|fm|, eps) ; out = relu(fm/denom) @ U
// 256 thr (4 waves), 64 rows/block, 512 blocks (2/CU, LDS-capped).
__global__ __launch_bounds__(256, 2) void main_kernel(
    const float* __restrict__ x1,
    const unsigned short* __restrict__ Mg,   // bf16, already in frag order (4096 x uint4)
    const float* __restrict__ cg,            // [64]
    const float* __restrict__ U,             // [64]
    float* __restrict__ out)                 // [32768]
{
    __shared__ uint4 Mlds[4096];   // 64 KB

    int tid  = threadIdx.x;
    int wave = tid >> 6;
    int lane = tid & 63;

    // Async linear staging: LDS dst = wave-uniform base + lane*16. 16 x 1KB per wave.
    const uint4* Msrc = (const uint4*)Mg;
    #pragma unroll
    for (int it = 0; it < 16; ++it) {
        int base = it * 256 + wave * 64;
        async_copy16(Msrc + base + lane, &Mlds[base]);
    }
    __syncthreads();   // drains vmcnt(0)

    int q  = lane >> 4;     // quad
    int fl = lane & 15;

    int row0 = blockIdx.x * 64 + wave * 16;
    const float* arow = x1 + (size_t)(row0 + fl) * DDIM + q * 8;

    const bf16x8* Mf = (const bf16x8*)Mlds;

    f32x4 acc0 = {0.f,0.f,0.f,0.f}, acc1 = {0.f,0.f,0.f,0.f};
    f32x4 acc2 = {0.f,0.f,0.f,0.f}, acc3 = {0.f,0.f,0.f,0.f};

    #pragma unroll 4
    for (int ks = 0; ks < 16; ++ks) {
        float4 av0 = *(const float4*)(arow + ks * 32);
        float4 av1 = *(const float4*)(arow + ks * 32 + 4);

        union { bf16x8 v; unsigned u32[4]; } af;
        af.u32[0] = pack2_bf16(av0.x, av0.y);
        af.u32[1] = pack2_bf16(av0.z, av0.w);
        af.u32[2] = pack2_bf16(av1.x, av1.y);
        af.u32[3] = pack2_bf16(av1.z, av1.w);

        bf16x8 b0 = Mf[(ks * 4 + 0) * 64 + lane];
        bf16x8 b1 = Mf[(ks * 4 + 1) * 64 + lane];
        bf16x8 b2 = Mf[(ks * 4 + 2) * 64 + lane];
        bf16x8 b3 = Mf[(ks * 4 + 3) * 64 + lane];

        acc0 = __builtin_amdgcn_mfma_f32_16x16x32_bf16(af.v, b0, acc0, 0, 0, 0);
        acc1 = __builtin_amdgcn_mfma_f32_16x16x32_bf16(af.v, b1, acc1, 0, 0, 0);
        acc2 = __builtin_amdgcn_mfma_f32_16x16x32_bf16(af.v, b2, acc2, 0, 0, 0);
        acc3 = __builtin_amdgcn_mfma_f32_16x16x32_bf16(af.v, b3, acc3, 0, 0, 0);
    }

    // Epilogue. C/D layout: col(f_local)=lane&15, row=q*4+reg.
    float cf0 = cg[fl], cf1 = cg[16 + fl], cf2 = cg[32 + fl], cf3 = cg[48 + fl];
    float uf0 = U[fl],  uf1 = U[16 + fl],  uf2 = U[32 + fl],  uf3 = U[48 + fl];

    #pragma unroll
    for (int r = 0; r < 4; ++r) {
        float f0 = acc0[r] + cf0;
        float f1 = acc1[r] + cf1;
        float f2 = acc2[r] + cf2;
        float f3 = acc3[r] + cf3;

        float s = fabsf(f0) + fabsf(f1) + fabsf(f2) + fabsf(f3);
        s += __shfl_xor(s, 1); s += __shfl_xor(s, 2);
        s += __shfl_xor(s, 4); s += __shfl_xor(s, 8);
        float denom = fmaxf(s, 1e-12f);

        float o = fmaxf(f0, 0.f) * uf0 + fmaxf(f1, 0.f) * uf1
                + fmaxf(f2, 0.f) * uf2 + fmaxf(f3, 0.f) * uf3;
        o += __shfl_xor(o, 1); o += __shfl_xor(o, 2);
        o += __shfl_xor(o, 4); o += __shfl_xor(o, 8);

        if (fl == 0) {
            out[row0 + q * 4 + r] = o / denom;
        }
    }
}

extern "C" void kernel_launch(void* const* d_in, const int* in_sizes, int n_in,
                              void* d_out, int out_size, void* d_ws, size_t ws_size,
                              hipStream_t stream) {
    const float* x1 = (const float*)d_in[0];
    const float* x2 = (const float*)d_in[1];
    const float* V  = (const float*)d_in[2];
    const float* W  = (const float*)d_in[3];
    const float* b  = (const float*)d_in[4];
    const float* U  = (const float*)d_in[5];
    float* outp = (float*)d_out;

    unsigned short* M = (unsigned short*)d_ws;                   // 64*512 bf16 = 64 KB (frag order)
    float* c          = (float*)((char*)d_ws + FDIM * DDIM * 2); // 64 fp32

    // rows = F*D (M) + F (c) = 32832; 4 waves/block -> 8208 blocks
    prep_kernel<<<8208, 256, 0, stream>>>(x2, V, W, b, M, c);
    // 32768 rows / 64 per block = 512 blocks
    main_kernel<<<512, 256, 0, stream>>>(x1, M, c, U, outp);
}